// Round 1
// baseline (542.392 us; speedup 1.0000x reference)
//
#include <hip/hip_runtime.h>

// Problem constants (from reference)
#define N_ROWS 100000
#define M_NBR  12
#define C_DIM  64
#define F_DIM  41
#define E_TOT  (N_ROWS * M_NBR)
#define W1P    44   // W1 row stride padded to multiple of 4 floats (16B) for ds_read_b128

// s_e = (softplus(x_e @ W1 + b1) . w2[:,0] + b2[0]) * INV_SQRT_4PI / M
__global__ __launch_bounds__(256) void edge_mlp_kernel(
    const float* __restrict__ nbr_fea,   // [E, F]
    const float* __restrict__ w1,        // [F, F]
    const float* __restrict__ b1,        // [F]
    const float* __restrict__ w2,        // [F, 9]
    const float* __restrict__ b2,        // [9]
    float* __restrict__ s_out)           // [E]
{
    __shared__ float lw1[F_DIM * W1P];   // 7216 B, [k][j] padded rows (16B aligned)
    __shared__ float lb1[W1P];
    __shared__ float lw2c[W1P];
    __shared__ float lx[256 * F_DIM];    // 42 KB, stride 41 (odd -> 2-way bank alias = free)

    const int tid = threadIdx.x;

    // Stage weights
    for (int idx = tid; idx < F_DIM * W1P; idx += 256) {
        int k = idx / W1P, j = idx - k * W1P;
        lw1[idx] = (j < F_DIM) ? w1[k * F_DIM + j] : 0.0f;
    }
    if (tid < W1P) {
        lb1[tid]  = (tid < F_DIM) ? b1[tid] : 0.0f;
        lw2c[tid] = (tid < F_DIM) ? w2[tid * 9] : 0.0f;  // column 0 of w2 only
    }

    const long base = (long)blockIdx.x * 256;
    long rem = (long)E_TOT - base;
    const int nedge = rem < 256 ? (int)rem : 256;

    // Stage this block's nbr_fea tile, fully coalesced
    const float* gx = nbr_fea + base * F_DIM;
    const int tot = nedge * F_DIM;
    for (int idx = tid; idx < tot; idx += 256) lx[idx] = gx[idx];
    __syncthreads();

    if (tid < nedge) {
        float h[W1P];
        #pragma unroll
        for (int j = 0; j < W1P; ++j) h[j] = lb1[j];

        const float* xr = lx + tid * F_DIM;
        for (int k = 0; k < F_DIM; ++k) {
            float xk = xr[k];                       // per-lane ds_read_b32 (conflict-free)
            const float* wrow = lw1 + k * W1P;      // broadcast ds_read_b128 x11
            #pragma unroll
            for (int j = 0; j < W1P; ++j) h[j] = fmaf(xk, wrow[j], h[j]);
        }

        float acc = b2[0];
        #pragma unroll
        for (int j = 0; j < F_DIM; ++j) {
            float v = h[j];
            // softplus(v) = max(v,0) + log(1 + exp(-|v|))  (numerically stable)
            float sp = fmaxf(v, 0.0f) + __logf(1.0f + __expf(-fabsf(v)));
            acc = fmaf(sp, lw2c[j], acc);
        }
        // fold integral normalization (1/sqrt(4pi)) and scatter-mean (1/M)
        s_out[base + tid] = acc * (0.28209479177387814f / 12.0f);
    }
}

// acc_i = sum_j s_ij * atom_fea[src_ij]; out = acc @ (tp_w/8)
__global__ __launch_bounds__(256) void gather_transform_kernel(
    const float* __restrict__ atom_fea,  // [N, C]
    const int*   __restrict__ nbr_idx,   // [N, M]
    const float* __restrict__ s,         // [E]
    const float* __restrict__ tp_w,      // [C, C]
    float* __restrict__ out)             // [N, C]
{
    __shared__ float accL[64 * C_DIM];   // 16 KB

    const int tid = threadIdx.x;
    const int c  = tid & 63;             // lane = channel
    const int rq = tid >> 6;             // wave id 0..3

    // Per-lane column of tp_w, pre-scaled by path norm 1/sqrt(C)=1/8
    float Tc[64];
    #pragma unroll
    for (int k = 0; k < 64; ++k) Tc[k] = tp_w[k * 64 + c] * 0.125f;

    const int row0 = blockIdx.x * 64;

    float acc[16];
    #pragma unroll
    for (int i = 0; i < 16; ++i) acc[i] = 0.0f;

    for (int i = 0; i < 16; ++i) {
        int r = row0 + rq * 16 + i;      // uniform within wave
        if (r < N_ROWS) {
            const int*   ir = nbr_idx + (long)r * M_NBR;
            const float* sr = s       + (long)r * M_NBR;
            #pragma unroll
            for (int j = 0; j < M_NBR; ++j) {
                int   idx = ir[j];
                float sv  = sr[j];
                acc[i] = fmaf(sv, atom_fea[(long)idx * C_DIM + c], acc[i]);
            }
        }
    }

    #pragma unroll
    for (int i = 0; i < 16; ++i)
        accL[(rq * 16 + i) * C_DIM + c] = acc[i];   // coalesced, 2-way alias = free
    __syncthreads();

    for (int i = 0; i < 16; ++i) {
        int rl = rq * 16 + i;
        int r  = row0 + rl;
        if (r >= N_ROWS) continue;
        const float* ar = accL + rl * C_DIM;        // broadcast ds_read_b128 x16
        float o = 0.0f;
        #pragma unroll
        for (int k = 0; k < 64; ++k) o = fmaf(ar[k], Tc[k], o);
        out[(long)r * C_DIM + c] = o;               // coalesced
    }
}

extern "C" void kernel_launch(void* const* d_in, const int* in_sizes, int n_in,
                              void* d_out, int out_size, void* d_ws, size_t ws_size,
                              hipStream_t stream) {
    const float* atom_fea = (const float*)d_in[0];
    const float* nbr_fea  = (const float*)d_in[1];
    const int*   nbr_idx  = (const int*)  d_in[2];
    // d_in[3] = pos : provably dead (only l=0 SH channel couples; it is constant)
    const float* w1   = (const float*)d_in[4];
    const float* b1   = (const float*)d_in[5];
    const float* w2   = (const float*)d_in[6];
    const float* b2   = (const float*)d_in[7];
    const float* tp_w = (const float*)d_in[8];

    float* s   = (float*)d_ws;           // E_TOT floats = 4.8 MB scratch
    float* out = (float*)d_out;

    const int blocksA = (E_TOT + 255) / 256;
    edge_mlp_kernel<<<blocksA, 256, 0, stream>>>(nbr_fea, w1, b1, w2, b2, s);

    const int blocksB = (N_ROWS + 63) / 64;
    gather_transform_kernel<<<blocksB, 256, 0, stream>>>(atom_fea, nbr_idx, s, tp_w, out);
}

// Round 2
// 480.685 us; speedup vs baseline: 1.1284x; 1.1284x over previous
//
#include <hip/hip_runtime.h>

#define N_ROWS 100000
#define M_NBR  12
#define C_DIM  64
#define F_DIM  41
#define E_TOT  (N_ROWS * M_NBR)

// ---------------------------------------------------------------------------
// Kernel A: s_e = (softplus(x_e @ W1 + b1) . w2[:,0] + b2[0]) * c
// Weights read via wave-uniform addresses -> scalar loads (s_load) -> the
// inner loop is v_fmac with an SGPR operand: no LDS, no vector-mem in loop.
// ---------------------------------------------------------------------------
__global__ __launch_bounds__(256) void edge_mlp_kernel(
    const float* __restrict__ nbr_fea,   // [E, F]
    const float* __restrict__ w1,        // [F, F]
    const float* __restrict__ b1,        // [F]
    const float* __restrict__ w2,        // [F, 9]
    const float* __restrict__ b2,        // [9]
    float* __restrict__ s_out)           // [E]
{
    __shared__ float lx[256 * F_DIM];    // 42 KB: coalesced-staged x tile

    const int tid  = threadIdx.x;
    const long base = (long)blockIdx.x * 256;
    int rem = (int)((long)E_TOT - base);
    const int nedge = rem < 256 ? rem : 256;

    const float* gx = nbr_fea + base * F_DIM;
    const int tot = nedge * F_DIM;
    for (int i = tid; i < tot; i += 256) lx[i] = gx[i];
    __syncthreads();

    if (tid < nedge) {
        float h[F_DIM];
        #pragma unroll
        for (int j = 0; j < F_DIM; ++j) h[j] = b1[j];          // scalar loads

        const float* xr = lx + tid * F_DIM;                    // stride 41: odd, conflict-free
        #pragma unroll 2
        for (int k = 0; k < F_DIM; ++k) {
            float xk = xr[k];                                  // ds_read_b32, ~5.8 cyc
            const float* wrow = w1 + k * F_DIM;                // uniform addr -> s_load
            #pragma unroll
            for (int j = 0; j < F_DIM; ++j) h[j] = fmaf(xk, wrow[j], h[j]);
        }

        float acc = b2[0];
        #pragma unroll
        for (int j = 0; j < F_DIM; ++j) {
            float v = h[j];
            float sp = fmaxf(v, 0.0f) + __logf(1.0f + __expf(-fabsf(v)));
            acc = fmaf(sp, w2[j * 9], acc);                    // w2 col 0, scalar loads
        }
        s_out[base + tid] = acc * (0.28209479177387814f / 12.0f);
    }
}

// ---------------------------------------------------------------------------
// Kernel B1: afT = atom_fea @ (tp_w / 8).  Transform commutes with the
// gather-sum (linearity), so apply it ONCE over N instead of per-edge-sum.
// Row values read via uniform addresses (s_load); T column per-lane in VGPRs.
// ---------------------------------------------------------------------------
__global__ __launch_bounds__(256) void atom_transform_kernel(
    const float* __restrict__ atom_fea,  // [N, C]
    const float* __restrict__ tp_w,      // [C, C]
    float* __restrict__ afT)             // [N, C]
{
    const int tid = threadIdx.x;
    const int c   = tid & 63;
    const int wv  = tid >> 6;

    float Tc[64];
    #pragma unroll
    for (int k = 0; k < 64; ++k) Tc[k] = tp_w[k * 64 + c] * 0.125f;  // coalesced

    const int row0 = blockIdx.x * 64 + wv * 16;
    for (int i = 0; i < 16; ++i) {
        int r = row0 + i;                       // wave-uniform
        if (r >= N_ROWS) break;
        const float* ar = atom_fea + (long)r * C_DIM;   // uniform -> s_load
        float o = 0.0f;
        #pragma unroll
        for (int k = 0; k < 64; ++k) o = fmaf(ar[k], Tc[k], o);
        afT[(long)r * C_DIM + c] = o;                   // coalesced
    }
}

// ---------------------------------------------------------------------------
// Kernel B2: out[r][:] = sum_j s_rj * afT[idx_rj][:].  Pure gather + 12 FMA,
// float4 per lane, 4 rows in flight per wave, no LDS.
// ---------------------------------------------------------------------------
__global__ __launch_bounds__(256) void gather_kernel(
    const float* __restrict__ afT,       // [N, C]
    const int*   __restrict__ nbr_idx,   // [N, M]
    const float* __restrict__ s,         // [E]
    float* __restrict__ out)             // [N, C]
{
    const int tid  = threadIdx.x;
    const int lane = tid & 63;
    const int wv   = tid >> 6;
    const int q    = lane >> 4;          // row-in-chunk 0..3
    const int c4   = (lane & 15) * 4;    // channel offset

    const int row0 = blockIdx.x * 32 + wv * 8;   // 8 rows per wave (N = 3125*32)

    #pragma unroll
    for (int ch = 0; ch < 2; ++ch) {
        int r = row0 + ch * 4 + q;
        const int*   ir = nbr_idx + r * M_NBR;
        const float* sr = s       + r * M_NBR;
        float4 acc = make_float4(0.f, 0.f, 0.f, 0.f);
        #pragma unroll
        for (int j = 0; j < M_NBR; ++j) {
            int   idx = ir[j];
            float sv  = sr[j];
            const float4 a = *(const float4*)(afT + (long)idx * C_DIM + c4);
            acc.x = fmaf(sv, a.x, acc.x);
            acc.y = fmaf(sv, a.y, acc.y);
            acc.z = fmaf(sv, a.z, acc.z);
            acc.w = fmaf(sv, a.w, acc.w);
        }
        *(float4*)(out + (long)r * C_DIM + c4) = acc;   // coalesced
    }
}

// ---------------------------------------------------------------------------
// Fallback (ws too small for afT): fused gather + LDS-epilogue transform.
// ---------------------------------------------------------------------------
__global__ __launch_bounds__(256) void gather_transform_kernel(
    const float* __restrict__ atom_fea,
    const int*   __restrict__ nbr_idx,
    const float* __restrict__ s,
    const float* __restrict__ tp_w,
    float* __restrict__ out)
{
    __shared__ float accL[64 * C_DIM];
    const int tid = threadIdx.x;
    const int c  = tid & 63;
    const int rq = tid >> 6;

    float Tc[64];
    #pragma unroll
    for (int k = 0; k < 64; ++k) Tc[k] = tp_w[k * 64 + c] * 0.125f;

    const int row0 = blockIdx.x * 64;
    for (int i = 0; i < 16; ++i) {
        int r = row0 + rq * 16 + i;
        float a = 0.0f;
        if (r < N_ROWS) {
            const int*   ir = nbr_idx + (long)r * M_NBR;
            const float* sr = s       + (long)r * M_NBR;
            #pragma unroll
            for (int j = 0; j < M_NBR; ++j)
                a = fmaf(sr[j], atom_fea[(long)ir[j] * C_DIM + c], a);
        }
        accL[(rq * 16 + i) * C_DIM + c] = a;
    }
    __syncthreads();
    for (int i = 0; i < 16; ++i) {
        int rl = rq * 16 + i;
        int r  = row0 + rl;
        if (r >= N_ROWS) continue;
        const float* ar = accL + rl * C_DIM;
        float o = 0.0f;
        #pragma unroll
        for (int k = 0; k < 64; ++k) o = fmaf(ar[k], Tc[k], o);
        out[(long)r * C_DIM + c] = o;
    }
}

extern "C" void kernel_launch(void* const* d_in, const int* in_sizes, int n_in,
                              void* d_out, int out_size, void* d_ws, size_t ws_size,
                              hipStream_t stream) {
    const float* atom_fea = (const float*)d_in[0];
    const float* nbr_fea  = (const float*)d_in[1];
    const int*   nbr_idx  = (const int*)  d_in[2];
    // d_in[3] = pos : dead (only the constant l=0 SH channel couples)
    const float* w1   = (const float*)d_in[4];
    const float* b1   = (const float*)d_in[5];
    const float* w2   = (const float*)d_in[6];
    const float* b2   = (const float*)d_in[7];
    const float* tp_w = (const float*)d_in[8];

    float* s   = (float*)d_ws;                       // 4.8 MB
    float* out = (float*)d_out;

    const int blocksA = (E_TOT + 255) / 256;
    edge_mlp_kernel<<<blocksA, 256, 0, stream>>>(nbr_fea, w1, b1, w2, b2, s);

    const size_t sBytes   = (size_t)E_TOT * sizeof(float);          // 4,800,000 (16B-mult)
    const size_t afTBytes = (size_t)N_ROWS * C_DIM * sizeof(float); // 25.6 MB

    if (ws_size >= sBytes + afTBytes) {
        float* afT = (float*)((char*)d_ws + sBytes);
        const int blocksT = (N_ROWS + 63) / 64;
        atom_transform_kernel<<<blocksT, 256, 0, stream>>>(atom_fea, tp_w, afT);
        const int blocksG = N_ROWS / 32;             // 3125, exact
        gather_kernel<<<blocksG, 256, 0, stream>>>(afT, nbr_idx, s, out);
    } else {
        const int blocksB = (N_ROWS + 63) / 64;
        gather_transform_kernel<<<blocksB, 256, 0, stream>>>(atom_fea, nbr_idx, s, tp_w, out);
    }
}